// Round 5
// baseline (254.547 us; speedup 1.0000x reference)
//
#include <hip/hip_runtime.h>

#define NH 4
#define DH 64
#define SS 1024
#define CC 256
#define BB 32

typedef __attribute__((ext_vector_type(8))) short short8;
typedef __attribute__((ext_vector_type(4))) float floatx4;

#define MFMA16(a, b, c) __builtin_amdgcn_mfma_f32_16x16x32_bf16(a, b, c, 0, 0, 0)

// q scale 0.125 folded with log2(e) so attention can use exp2 directly
#define QSCALE 0.18033688011112042f

__device__ __forceinline__ short f2bf(float f) {
    union { float f; unsigned u; } v; v.f = f;
    unsigned r = (v.u + 0x7fffu + ((v.u >> 16) & 1u)) >> 16;
    return (short)r;
}
__device__ __forceinline__ unsigned bfrn(float f) {  // round-nearest bf16 bits
    union { float f; unsigned u; } v; v.f = f;
    return (v.u + 0x7fffu + ((v.u >> 16) & 1u)) >> 16;
}
// pack two floats to bf16x2 (truncate — P values, rel err ~0.4% ok)
__device__ __forceinline__ unsigned pk2_trunc(float a, float b) {
    union { float f; unsigned u; } ua, ub; ua.f = a; ub.f = b;
    return (ua.u >> 16) | (ub.u & 0xFFFF0000u);
}
__device__ __forceinline__ unsigned pk2_rn(float a, float b) {
    return bfrn(a) | (bfrn(b) << 16);
}

// ------- merged prep: x [B][C][S] f32 -> xs [B][S][C] bf16 ; weight transposes -------
__global__ __launch_bounds__(256) void k_prep(const float* __restrict__ x,
                                              const float* __restrict__ Wqkv,
                                              const float* __restrict__ Wout,
                                              short* __restrict__ xs,
                                              short* __restrict__ Wqkv_t,
                                              short* __restrict__ Wout_t) {
    int bid = blockIdx.x;
    if (bid < 2048) {
        __shared__ float tile[64][65];
        int b = bid >> 6;
        int s0 = ((bid >> 2) & 15) * 64;
        int c0 = (bid & 3) * 64;
        int t = threadIdx.x;
        int tx = t & 63, ty = t >> 6;
        for (int i = 0; i < 16; ++i) {
            int c = ty + i * 4;
            tile[tx][c] = x[((b * CC) + (c0 + c)) * SS + s0 + tx];
        }
        __syncthreads();
        for (int i = 0; i < 8; ++i) {
            int s = (t >> 5) + i * 8;
            int cp = (t & 31) * 2;
            short2 v;
            v.x = f2bf(tile[s][cp]);
            v.y = f2bf(tile[s][cp + 1]);
            *(short2*)(&xs[((b * SS) + (s0 + s)) * CC + c0 + cp]) = v;
        }
    } else {
        int idx = (bid - 2048) * 256 + threadIdx.x;
        if (idx < 768 * 256) {
            int n = idx >> 8, k = idx & 255;
            Wqkv_t[idx] = f2bf(Wqkv[k * 768 + n]);
        } else {
            int j = idx - 768 * 256;
            int c = j >> 8, k = j & 255;
            Wout_t[j] = f2bf(Wout[k * 256 + c]);
        }
    }
}

// ---------------- QKV GEMM: [32768,256] @ [256,768], LDS-routed epilogue -------
// Grid 1536 linear, swizzled so one m-tile's 6 n-blocks share an XCD (A L2 reuse).
__global__ __launch_bounds__(256) void k_qkv(const short* __restrict__ xs,
                                             const short* __restrict__ Wt,
                                             const float* __restrict__ bqkv,
                                             short* __restrict__ qw,
                                             short* __restrict__ kw,
                                             short* __restrict__ vtw) {
    __shared__ short smem[10240];  // As | Bs in loop; epilogue staging tile after
    short* As = smem;
    short* Bs = smem + 5120;
    int bid = blockIdx.x;
    int idx = bid >> 3;
    int m0 = ((bid & 7) * 32 + idx / 6) * 128;
    int n0 = (idx % 6) * 128;
    int t = threadIdx.x;
    int lane = t & 63, wid = t >> 6;
    int wr = wid >> 1, wc = wid & 1;
    int c16 = lane & 15, qd = lane >> 4;

    floatx4 acc[4][4] = {};
    short8 pa[2], pb[2];

    {
        for (int j = 0; j < 2; ++j) {
            int id = j * 256 + t, row = id >> 2, cc = id & 3;
            pa[j] = *(const short8*)(&xs[(m0 + row) * CC + cc * 8]);
            pb[j] = *(const short8*)(&Wt[(n0 + row) * CC + cc * 8]);
        }
    }
    for (int kt = 0; kt < 8; ++kt) {
        if (kt) __syncthreads();
        for (int j = 0; j < 2; ++j) {
            int id = j * 256 + t, row = id >> 2, cc = id & 3;
            *(short8*)(&As[row * 40 + cc * 8]) = pa[j];
            *(short8*)(&Bs[row * 40 + cc * 8]) = pb[j];
        }
        __syncthreads();
        if (kt < 7) {
            for (int j = 0; j < 2; ++j) {
                int id = j * 256 + t, row = id >> 2, cc = id & 3;
                pa[j] = *(const short8*)(&xs[(m0 + row) * CC + (kt + 1) * 32 + cc * 8]);
                pb[j] = *(const short8*)(&Wt[(n0 + row) * CC + (kt + 1) * 32 + cc * 8]);
            }
        }
        short8 av[4], bv[4];
        for (int i = 0; i < 4; ++i) {
            av[i] = *(const short8*)(&As[(wr * 64 + i * 16 + c16) * 40 + qd * 8]);
            bv[i] = *(const short8*)(&Bs[(wc * 64 + i * 16 + c16) * 40 + qd * 8]);
        }
        for (int mi = 0; mi < 4; ++mi)
            for (int ni = 0; ni < 4; ++ni)
                acc[mi][ni] = MFMA16(av[mi], bv[ni], acc[mi][ni]);
    }

    int b = m0 >> 10, sbase = m0 & 1023;
    float bias4[4];
    for (int ni = 0; ni < 4; ++ni)
        bias4[ni] = bqkv[n0 + wc * 64 + ni * 16 + c16];

    for (int half = 0; half < 2; ++half) {
        int seg = (n0 >> 6) + half;
        int sel = seg % 3, h = seg / 3;
        int bh = b * NH + h;
        __syncthreads();
        if (wc == half) {
            if (sel == 2) {
                // V: stage transposed [d][s_local], stride 136 (16B-aligned rows)
                for (int mi = 0; mi < 4; ++mi)
                    for (int ni = 0; ni < 4; ++ni)
                        for (int r = 0; r < 4; ++r)
                            smem[(ni * 16 + c16) * 136 + wr * 64 + mi * 16 + qd * 4 + r] =
                                f2bf(acc[mi][ni][r] + bias4[ni]);
            } else {
                // Q/K: stage [s_local][d], stride 80 (16B-aligned rows)
                float sc = (sel == 0) ? QSCALE : 1.f;
                for (int mi = 0; mi < 4; ++mi)
                    for (int ni = 0; ni < 4; ++ni)
                        for (int r = 0; r < 4; ++r)
                            smem[(wr * 64 + mi * 16 + qd * 4 + r) * 80 + ni * 16 + c16] =
                                f2bf((acc[mi][ni][r] + bias4[ni]) * sc);
            }
        }
        __syncthreads();
        if (sel == 2) {
            for (int i = 0; i < 4; ++i) {
                int d = (t >> 4) + i * 16;
                int sc8 = (t & 15) * 8;
                *(short8*)(&vtw[(bh * DH + d) * SS + sbase + sc8]) =
                    *(const short8*)(&smem[d * 136 + sc8]);
            }
        } else {
            short* dst = (sel == 0) ? qw : kw;
            for (int i = 0; i < 4; ++i) {
                int srow = (t >> 3) + i * 32;
                int d8 = (t & 7) * 8;
                *(short8*)(&dst[(bh * SS + sbase + srow) * DH + d8]) =
                    *(const short8*)(&smem[srow * 80 + d8]);
            }
        }
    }
}

// ---- flash attention, barrier-free: K/V MFMA fragments are 16B-contiguous in
// ---- global (kw [s][d], vtw [d][s]) so they load straight to VGPRs; the block's
// ---- 16KB K/V tile stays L1-resident across its 4 waves, L2 across q-blocks.
// ---- Only P^T round-trips through (per-wave, per-g) LDS.
__global__ __launch_bounds__(256) void k_attn(const short* __restrict__ qw,
                                              const short* __restrict__ kw,
                                              const short* __restrict__ vtw,
                                              short* __restrict__ res) {
    __shared__ __align__(16) short Pt[4 * 2 * 16 * 76];  // [wave][g][s][j]
    // XCD swizzle: bh = id & 127 puts a bh's 8 q-tiles on the same XCD
    int bid = blockIdx.x;
    int q0 = (bid >> 7) * 128;
    int bh = bid & 127;
    int t = threadIdx.x;
    int lane = t & 63, w = t >> 6;
    int c16 = lane & 15, qd = lane >> 4;
    const short* qp = qw + bh * SS * DH;
    // lane-resolved fragment bases
    const short* kpl = kw + (size_t)bh * SS * DH + c16 * DH + qd * 8;
    const short* vpl = vtw + (size_t)bh * DH * SS + (size_t)c16 * SS + qd * 8;

    short8 qfrag[2][2];
    for (int g = 0; g < 2; ++g)
        for (int ks = 0; ks < 2; ++ks)
            qfrag[g][ks] = *(const short8*)(
                &qp[(q0 + g * 64 + w * 16 + c16) * DH + ks * 32 + qd * 8]);

    float l_i[2] = {};
    floatx4 o_acc[2][4] = {};

    int pb0 = w * 2 * 16 * 76;
    for (int kt = 0; kt < 16; ++kt) {
        // K frag: rows j = kt*64 + ji*16 + c16, cols d = ks*32 + qd*8..+7
        // V frag: rows d = ji*16 + c16,        cols j = kt*64 + ks*32 + qd*8..+7
        short8 kf[2][4], vf[2][4];
        for (int ji = 0; ji < 4; ++ji)
            for (int ks = 0; ks < 2; ++ks) {
                kf[ks][ji] = *(const short8*)(kpl + (kt * 64 + ji * 16) * DH + ks * 32);
                vf[ks][ji] = *(const short8*)(vpl + (size_t)(ji * 16) * SS + kt * 64 + ks * 32);
            }

        for (int g = 0; g < 2; ++g) {
            int pbase = pb0 + g * 16 * 76;
            // S^T[j][s]: A = K rows (m=j), B = Q cols (n=s)
            floatx4 sacc[4] = {};
            for (int ks = 0; ks < 2; ++ks)
                for (int ji = 0; ji < 4; ++ji)
                    sacc[ji] = MFMA16(kf[ks][ji], qfrag[g][ks], sacc[ji]);

            // exp2 -> P^T; 4 consecutive j per lane pack to one b64 LDS write
            for (int ji = 0; ji < 4; ++ji) {
                float e0 = __builtin_amdgcn_exp2f(sacc[ji][0]);
                float e1 = __builtin_amdgcn_exp2f(sacc[ji][1]);
                float e2 = __builtin_amdgcn_exp2f(sacc[ji][2]);
                float e3 = __builtin_amdgcn_exp2f(sacc[ji][3]);
                l_i[g] += (e0 + e1) + (e2 + e3);
                uint2 pw;
                pw.x = pk2_trunc(e0, e1);
                pw.y = pk2_trunc(e2, e3);
                *(uint2*)(&Pt[pbase + c16 * 76 + ji * 16 + qd * 4]) = pw;
            }

            // O^T[d][s] += V^T · P^T  (in-wave DS ordering covers the Pt RAW)
            for (int ks2 = 0; ks2 < 2; ++ks2) {
                short8 pf = *(const short8*)(&Pt[pbase + c16 * 76 + ks2 * 32 + qd * 8]);
                for (int di = 0; di < 4; ++di)
                    o_acc[g][di] = MFMA16(vf[ks2][di], pf, o_acc[g][di]);
            }
        }
    }

    // l partials: lane (qd,c16) summed its 16 j's for q-row s=c16; combine qd groups
    for (int g = 0; g < 2; ++g) {
        float l = l_i[g];
        l += __shfl_xor(l, 16);
        l += __shfl_xor(l, 32);
        l_i[g] = 1.f / l;
    }

    int b = bh >> 2, h = bh & 3;
    for (int g = 0; g < 2; ++g) {
        int s = q0 + g * 64 + w * 16 + c16;
        long base = (long)(b * SS + s) * CC + h * DH;
        float inv = l_i[g];
        for (int di = 0; di < 4; ++di) {
            uint2 ow;
            ow.x = pk2_rn(o_acc[g][di][0] * inv, o_acc[g][di][1] * inv);
            ow.y = pk2_rn(o_acc[g][di][2] * inv, o_acc[g][di][3] * inv);
            *(uint2*)(&res[base + di * 16 + qd * 4]) = ow;
        }
    }
}

// ------- out GEMM (transposed): D[c][s] = sum_k res[s][k] W_out[k][c] + b + x -------
__global__ __launch_bounds__(256) void k_out(const short* __restrict__ res,
                                             const short* __restrict__ Wot,
                                             const float* __restrict__ bout,
                                             const float* __restrict__ x,
                                             float* __restrict__ out) {
    __shared__ short As[128 * 40];
    __shared__ short Bs[128 * 40];
    int b = blockIdx.z;
    int m0 = blockIdx.y * 128;  // c
    int n0 = blockIdx.x * 128;  // s
    int t = threadIdx.x;
    int lane = t & 63, wid = t >> 6;
    int wr = wid >> 1, wc = wid & 1;
    int c16 = lane & 15, qd = lane >> 4;

    floatx4 acc[4][4] = {};
    short8 pa[2], pbv[2];
    for (int j = 0; j < 2; ++j) {
        int id = j * 256 + t, row = id >> 2, cc = id & 3;
        pa[j] = *(const short8*)(&Wot[(m0 + row) * CC + cc * 8]);
        pbv[j] = *(const short8*)(&res[(b * SS + n0 + row) * CC + cc * 8]);
    }

    for (int kt = 0; kt < 8; ++kt) {
        if (kt) __syncthreads();
        for (int j = 0; j < 2; ++j) {
            int id = j * 256 + t, row = id >> 2, cc = id & 3;
            *(short8*)(&As[row * 40 + cc * 8]) = pa[j];
            *(short8*)(&Bs[row * 40 + cc * 8]) = pbv[j];
        }
        __syncthreads();
        if (kt < 7) {
            for (int j = 0; j < 2; ++j) {
                int id = j * 256 + t, row = id >> 2, cc = id & 3;
                pa[j] = *(const short8*)(&Wot[(m0 + row) * CC + (kt + 1) * 32 + cc * 8]);
                pbv[j] = *(const short8*)(&res[(b * SS + n0 + row) * CC + (kt + 1) * 32 + cc * 8]);
            }
        }
        short8 av[4], bv[4];
        for (int i = 0; i < 4; ++i) {
            av[i] = *(const short8*)(&As[(wr * 64 + i * 16 + c16) * 40 + qd * 8]);
            bv[i] = *(const short8*)(&Bs[(wc * 64 + i * 16 + c16) * 40 + qd * 8]);
        }
        for (int mi = 0; mi < 4; ++mi)
            for (int ni = 0; ni < 4; ++ni)
                acc[mi][ni] = MFMA16(av[mi], bv[ni], acc[mi][ni]);
    }

    for (int mi = 0; mi < 4; ++mi) {
        for (int r = 0; r < 4; ++r) {
            int c = m0 + wr * 64 + mi * 16 + qd * 4 + r;
            float bias = bout[c];
            for (int ni = 0; ni < 4; ++ni) {
                int s = n0 + wc * 64 + ni * 16 + c16;
                float v = acc[mi][ni][r] + bias + x[((b * CC) + c) * SS + s];
                out[((b * CC) + c) * SS + s] = v;
            }
        }
    }
}

extern "C" void kernel_launch(void* const* d_in, const int* in_sizes, int n_in,
                              void* d_out, int out_size, void* d_ws, size_t ws_size,
                              hipStream_t stream) {
    const float* x    = (const float*)d_in[0];
    const float* Wqkv = (const float*)d_in[1];
    const float* bqkv = (const float*)d_in[2];
    const float* Wout = (const float*)d_in[3];
    const float* bout = (const float*)d_in[4];
    float* out = (float*)d_out;

    char* ws = (char*)d_ws;
    short* xs_res = (short*)(ws);               // 16,777,216 B  (xs, later reused as res)
    short* qw     = (short*)(ws + 16777216);    // 16,777,216 B
    short* kw     = (short*)(ws + 33554432);    // 16,777,216 B
    short* vtw    = (short*)(ws + 50331648);    // 16,777,216 B
    short* Wqkv_t = (short*)(ws + 67108864);    //    393,216 B
    short* Wout_t = (short*)(ws + 67502080);    //    131,072 B

    k_prep<<<dim3(3072), 256, 0, stream>>>(x, Wqkv, Wout, xs_res, Wqkv_t, Wout_t);
    k_qkv<<<dim3(1536), 256, 0, stream>>>(xs_res, Wqkv_t, bqkv, qw, kw, vtw);
    k_attn<<<dim3(1024), 256, 0, stream>>>(qw, kw, vtw, xs_res);
    k_out<<<dim3(8, 2, 32), 256, 0, stream>>>(xs_res, Wout_t, bout, x, out);
}

// Round 6
// 177.466 us; speedup vs baseline: 1.4343x; 1.4343x over previous
//
#include <hip/hip_runtime.h>

#define NH 4
#define DH 64
#define SS 1024
#define CC 256
#define BB 32

typedef __attribute__((ext_vector_type(8))) short short8;
typedef __attribute__((ext_vector_type(4))) float floatx4;

#define MFMA16(a, b, c) __builtin_amdgcn_mfma_f32_16x16x32_bf16(a, b, c, 0, 0, 0)

// q scale 0.125 folded with log2(e) so attention can use exp2 directly
#define QSCALE 0.18033688011112042f

__device__ __forceinline__ short f2bf(float f) {
    union { float f; unsigned u; } v; v.f = f;
    unsigned r = (v.u + 0x7fffu + ((v.u >> 16) & 1u)) >> 16;
    return (short)r;
}
__device__ __forceinline__ unsigned bfrn(float f) {
    union { float f; unsigned u; } v; v.f = f;
    return (v.u + 0x7fffu + ((v.u >> 16) & 1u)) >> 16;
}
__device__ __forceinline__ unsigned pk2_trunc(float a, float b) {
    union { float f; unsigned u; } ua, ub; ua.f = a; ub.f = b;
    return (ua.u >> 16) | (ub.u & 0xFFFF0000u);
}
__device__ __forceinline__ unsigned pk2_rn(float a, float b) {
    return bfrn(a) | (bfrn(b) << 16);
}

// ------- merged prep: x [B][C][S] f32 -> xs [B][S][C] bf16 ; weight transposes -------
__global__ __launch_bounds__(256) void k_prep(const float* __restrict__ x,
                                              const float* __restrict__ Wqkv,
                                              const float* __restrict__ Wout,
                                              short* __restrict__ xs,
                                              short* __restrict__ Wqkv_t,
                                              short* __restrict__ Wout_t) {
    int bid = blockIdx.x;
    if (bid < 2048) {
        __shared__ float tile[64][65];
        int b = bid >> 6;
        int s0 = ((bid >> 2) & 15) * 64;
        int c0 = (bid & 3) * 64;
        int t = threadIdx.x;
        int tx = t & 63, ty = t >> 6;
        for (int i = 0; i < 16; ++i) {
            int c = ty + i * 4;
            tile[tx][c] = x[((b * CC) + (c0 + c)) * SS + s0 + tx];
        }
        __syncthreads();
        for (int i = 0; i < 8; ++i) {
            int s = (t >> 5) + i * 8;
            int cp = (t & 31) * 2;
            short2 v;
            v.x = f2bf(tile[s][cp]);
            v.y = f2bf(tile[s][cp + 1]);
            *(short2*)(&xs[((b * SS) + (s0 + s)) * CC + c0 + cp]) = v;
        }
    } else {
        int idx = (bid - 2048) * 256 + threadIdx.x;
        if (idx < 768 * 256) {
            int n = idx >> 8, k = idx & 255;
            Wqkv_t[idx] = f2bf(Wqkv[k * 768 + n]);
        } else {
            int j = idx - 768 * 256;
            int c = j >> 8, k = j & 255;
            Wout_t[j] = f2bf(Wout[k * 256 + c]);
        }
    }
}

// ---------------- QKV GEMM: [32768,256] @ [256,768] ----------------
// Q and V stored transposed [bh][d][s] -> direct uint2 epilogue stores.
// K stored [bh][s][d] (needed row-major for attn's kf b128 reads) via LDS.
__global__ __launch_bounds__(256) void k_qkv(const short* __restrict__ xs,
                                             const short* __restrict__ Wt,
                                             const float* __restrict__ bqkv,
                                             short* __restrict__ qtw,
                                             short* __restrict__ kw,
                                             short* __restrict__ vtw) {
    __shared__ short smem[10240];  // As | Bs in loop; K staging tile after
    short* As = smem;
    short* Bs = smem + 5120;
    int bid = blockIdx.x;
    int idx = bid >> 3;
    int m0 = ((bid & 7) * 32 + idx / 6) * 128;
    int n0 = (idx % 6) * 128;
    int t = threadIdx.x;
    int lane = t & 63, wid = t >> 6;
    int wr = wid >> 1, wc = wid & 1;
    int c16 = lane & 15, qd = lane >> 4;

    floatx4 acc[4][4] = {};
    short8 pa[2], pb[2];

    for (int j = 0; j < 2; ++j) {
        int id = j * 256 + t, row = id >> 2, cc = id & 3;
        pa[j] = *(const short8*)(&xs[(m0 + row) * CC + cc * 8]);
        pb[j] = *(const short8*)(&Wt[(n0 + row) * CC + cc * 8]);
    }
    for (int kt = 0; kt < 8; ++kt) {
        if (kt) __syncthreads();
        for (int j = 0; j < 2; ++j) {
            int id = j * 256 + t, row = id >> 2, cc = id & 3;
            *(short8*)(&As[row * 40 + cc * 8]) = pa[j];
            *(short8*)(&Bs[row * 40 + cc * 8]) = pb[j];
        }
        __syncthreads();
        if (kt < 7) {
            for (int j = 0; j < 2; ++j) {
                int id = j * 256 + t, row = id >> 2, cc = id & 3;
                pa[j] = *(const short8*)(&xs[(m0 + row) * CC + (kt + 1) * 32 + cc * 8]);
                pb[j] = *(const short8*)(&Wt[(n0 + row) * CC + (kt + 1) * 32 + cc * 8]);
            }
        }
        short8 av[4], bv[4];
        for (int i = 0; i < 4; ++i) {
            av[i] = *(const short8*)(&As[(wr * 64 + i * 16 + c16) * 40 + qd * 8]);
            bv[i] = *(const short8*)(&Bs[(wc * 64 + i * 16 + c16) * 40 + qd * 8]);
        }
        for (int mi = 0; mi < 4; ++mi)
            for (int ni = 0; ni < 4; ++ni)
                acc[mi][ni] = MFMA16(av[mi], bv[ni], acc[mi][ni]);
    }

    int b = m0 >> 10, sbase = m0 & 1023;
    // this wave owns one 64-col segment: seg = h*3 + part (part: 0=q,1=k,2=v)
    int seg = (n0 >> 6) + wc;
    int sel = seg % 3, h = seg / 3;
    int bh = b * NH + h;
    float bias4[4];
    for (int ni = 0; ni < 4; ++ni)
        bias4[ni] = bqkv[n0 + wc * 64 + ni * 16 + c16];

    if (sel != 1) {
        // Q (scaled) / V: direct transposed store [bh][d][s]; lane holds 4 consecutive s
        float sc = (sel == 0) ? QSCALE : 1.f;
        short* dst = (sel == 0) ? qtw : vtw;
        for (int ni = 0; ni < 4; ++ni) {
            int d = ni * 16 + c16;
            for (int mi = 0; mi < 4; ++mi) {
                int s = sbase + wr * 64 + mi * 16 + qd * 4;
                uint2 ow;
                ow.x = pk2_rn((acc[mi][ni][0] + bias4[ni]) * sc,
                              (acc[mi][ni][1] + bias4[ni]) * sc);
                ow.y = pk2_rn((acc[mi][ni][2] + bias4[ni]) * sc,
                              (acc[mi][ni][3] + bias4[ni]) * sc);
                *(uint2*)(&dst[(size_t)(bh * DH + d) * SS + s]) = ow;
            }
        }
    }

    // K segment (if this block has one): LDS transpose -> coalesced [s][d] store
    int seg0 = n0 >> 6;
    int kseg = (seg0 % 3 == 1) ? seg0 : (((seg0 + 1) % 3 == 1) ? seg0 + 1 : -1);
    if (kseg >= 0) {
        short* Kt = smem;  // 128*72 = 9216 shorts, As/Bs dead
        __syncthreads();
        if (seg == kseg) {
            for (int mi = 0; mi < 4; ++mi)
                for (int ni = 0; ni < 4; ++ni)
                    for (int r = 0; r < 4; ++r)
                        Kt[(wr * 64 + mi * 16 + qd * 4 + r) * 72 + ni * 16 + c16] =
                            f2bf(acc[mi][ni][r] + bias4[ni]);
        }
        __syncthreads();
        int bhk = b * NH + kseg / 3;
        int srow = t >> 1, dh = (t & 1) * 32;
        short* gdst = &kw[(size_t)(bhk * SS + sbase + srow) * DH + dh];
        const short* lsrc = &Kt[srow * 72 + dh];
        for (int k = 0; k < 4; ++k)
            *(short8*)(gdst + k * 8) = *(const short8*)(lsrc + k * 8);
    }
}

// ---- flash attention: 256 q-rows/block (g x 4 per wave) amortizes the kf/vf
// ---- LDS fragment reads (the R4 bottleneck) over 2x the MFMAs.
__global__ __launch_bounds__(256, 2) void k_attn(const short* __restrict__ qtw,
                                                 const short* __restrict__ kw,
                                                 const short* __restrict__ vtw,
                                                 short* __restrict__ res) {
    __shared__ __align__(16) short Ks[64 * 72];
    __shared__ __align__(16) short Vts[64 * 72];
    __shared__ __align__(16) short Pt[4 * 16 * 76];  // per-wave P^T[s][j]
    // XCD swizzle: bh = bid & 127 keeps a bh's q-blocks on one XCD
    int bid = blockIdx.x;
    int q0 = (bid >> 7) * 256;
    int bh = bid & 127;
    int t = threadIdx.x;
    int lane = t & 63, w = t >> 6;
    int c16 = lane & 15, qd = lane >> 4;
    const short* qp = qtw + (size_t)bh * DH * SS;  // [d][s]
    const short* kp = kw + (size_t)bh * SS * DH;   // [s][d]
    const short* vp = vtw + (size_t)bh * DH * SS;  // [d][s]

    // Q B-fragments: element j needs Q[s][d=ks*32+qd*8+j]; Q stored [d][s]
    short8 qfrag[4][2];
    for (int g = 0; g < 4; ++g) {
        int s = q0 + g * 64 + w * 16 + c16;
        for (int ks = 0; ks < 2; ++ks) {
            short8 q;
            for (int j = 0; j < 8; ++j)
                q[j] = qp[(size_t)(ks * 32 + qd * 8 + j) * SS + s];
            qfrag[g][ks] = q;
        }
    }

    float l_i[4] = {};
    floatx4 o_acc[4][4] = {};

    short8 kreg[2], vreg[2];
    for (int j = 0; j < 2; ++j) {
        int id = j * 256 + t, row = id >> 3, cc = id & 7;
        kreg[j] = *(const short8*)(&kp[row * DH + cc * 8]);
        vreg[j] = *(const short8*)(&vp[row * SS + cc * 8]);
    }

    int pbase = w * 16 * 76;
    for (int kt = 0; kt < 16; ++kt) {
        if (kt) __syncthreads();
        for (int j = 0; j < 2; ++j) {
            int id = j * 256 + t, row = id >> 3, cc = id & 7;
            *(short8*)(&Ks[row * 72 + cc * 8]) = kreg[j];
            *(short8*)(&Vts[row * 72 + cc * 8]) = vreg[j];
        }
        __syncthreads();
        if (kt < 15) {
            for (int j = 0; j < 2; ++j) {
                int id = j * 256 + t, row = id >> 3, cc = id & 7;
                kreg[j] = *(const short8*)(&kp[((kt + 1) * 64 + row) * DH + cc * 8]);
                vreg[j] = *(const short8*)(&vp[row * SS + (kt + 1) * 64 + cc * 8]);
            }
        }

        short8 kf[2][4], vf[2][4];
        for (int ks = 0; ks < 2; ++ks)
            for (int ji = 0; ji < 4; ++ji) {
                kf[ks][ji] = *(const short8*)(&Ks[(ji * 16 + c16) * 72 + ks * 32 + qd * 8]);
                vf[ks][ji] = *(const short8*)(&Vts[(ji * 16 + c16) * 72 + ks * 32 + qd * 8]);
            }

        for (int g = 0; g < 4; ++g) {
            // S^T[j][s]: A = K rows (m=j), B = Q cols (n=s)
            floatx4 sacc[4] = {};
            for (int ks = 0; ks < 2; ++ks)
                for (int ji = 0; ji < 4; ++ji)
                    sacc[ji] = MFMA16(kf[ks][ji], qfrag[g][ks], sacc[ji]);

            for (int ji = 0; ji < 4; ++ji) {
                float e0 = __builtin_amdgcn_exp2f(sacc[ji][0]);
                float e1 = __builtin_amdgcn_exp2f(sacc[ji][1]);
                float e2 = __builtin_amdgcn_exp2f(sacc[ji][2]);
                float e3 = __builtin_amdgcn_exp2f(sacc[ji][3]);
                l_i[g] += (e0 + e1) + (e2 + e3);
                uint2 pw;
                pw.x = pk2_trunc(e0, e1);
                pw.y = pk2_trunc(e2, e3);
                *(uint2*)(&Pt[pbase + c16 * 76 + ji * 16 + qd * 4]) = pw;
            }

            // O^T[d][s] += V^T · P^T (in-wave DS ordering covers Pt RAW/WAR)
            for (int ks2 = 0; ks2 < 2; ++ks2) {
                short8 pf = *(const short8*)(&Pt[pbase + c16 * 76 + ks2 * 32 + qd * 8]);
                for (int di = 0; di < 4; ++di)
                    o_acc[g][di] = MFMA16(vf[ks2][di], pf, o_acc[g][di]);
            }
        }
    }

    for (int g = 0; g < 4; ++g) {
        float l = l_i[g];
        l += __shfl_xor(l, 16);
        l += __shfl_xor(l, 32);
        l_i[g] = 1.f / l;
    }

    int b = bh >> 2, h = bh & 3;
    for (int g = 0; g < 4; ++g) {
        int s = q0 + g * 64 + w * 16 + c16;
        long base = (long)(b * SS + s) * CC + h * DH;
        float inv = l_i[g];
        for (int di = 0; di < 4; ++di) {
            uint2 ow;
            ow.x = pk2_rn(o_acc[g][di][0] * inv, o_acc[g][di][1] * inv);
            ow.y = pk2_rn(o_acc[g][di][2] * inv, o_acc[g][di][3] * inv);
            *(uint2*)(&res[base + di * 16 + qd * 4]) = ow;
        }
    }
}

// ------- out GEMM (transposed): D[c][s] = sum_k res[s][k] W_out[k][c] + b + x -------
__global__ __launch_bounds__(256) void k_out(const short* __restrict__ res,
                                             const short* __restrict__ Wot,
                                             const float* __restrict__ bout,
                                             const float* __restrict__ x,
                                             float* __restrict__ out) {
    __shared__ short As[128 * 40];
    __shared__ short Bs[128 * 40];
    int b = blockIdx.z;
    int m0 = blockIdx.y * 128;  // c
    int n0 = blockIdx.x * 128;  // s
    int t = threadIdx.x;
    int lane = t & 63, wid = t >> 6;
    int wr = wid >> 1, wc = wid & 1;
    int c16 = lane & 15, qd = lane >> 4;

    floatx4 acc[4][4] = {};
    short8 pa[2], pbv[2];
    for (int j = 0; j < 2; ++j) {
        int id = j * 256 + t, row = id >> 2, cc = id & 3;
        pa[j] = *(const short8*)(&Wot[(m0 + row) * CC + cc * 8]);
        pbv[j] = *(const short8*)(&res[(b * SS + n0 + row) * CC + cc * 8]);
    }

    for (int kt = 0; kt < 8; ++kt) {
        if (kt) __syncthreads();
        for (int j = 0; j < 2; ++j) {
            int id = j * 256 + t, row = id >> 2, cc = id & 3;
            *(short8*)(&As[row * 40 + cc * 8]) = pa[j];
            *(short8*)(&Bs[row * 40 + cc * 8]) = pbv[j];
        }
        __syncthreads();
        if (kt < 7) {
            for (int j = 0; j < 2; ++j) {
                int id = j * 256 + t, row = id >> 2, cc = id & 3;
                pa[j] = *(const short8*)(&Wot[(m0 + row) * CC + (kt + 1) * 32 + cc * 8]);
                pbv[j] = *(const short8*)(&res[(b * SS + n0 + row) * CC + (kt + 1) * 32 + cc * 8]);
            }
        }
        short8 av[4], bv[4];
        for (int i = 0; i < 4; ++i) {
            av[i] = *(const short8*)(&As[(wr * 64 + i * 16 + c16) * 40 + qd * 8]);
            bv[i] = *(const short8*)(&Bs[(wc * 64 + i * 16 + c16) * 40 + qd * 8]);
        }
        for (int mi = 0; mi < 4; ++mi)
            for (int ni = 0; ni < 4; ++ni)
                acc[mi][ni] = MFMA16(av[mi], bv[ni], acc[mi][ni]);
    }

    for (int mi = 0; mi < 4; ++mi) {
        for (int r = 0; r < 4; ++r) {
            int c = m0 + wr * 64 + mi * 16 + qd * 4 + r;
            float bias = bout[c];
            for (int ni = 0; ni < 4; ++ni) {
                int s = n0 + wc * 64 + ni * 16 + c16;
                float v = acc[mi][ni][r] + bias + x[((b * CC) + c) * SS + s];
                out[((b * CC) + c) * SS + s] = v;
            }
        }
    }
}

extern "C" void kernel_launch(void* const* d_in, const int* in_sizes, int n_in,
                              void* d_out, int out_size, void* d_ws, size_t ws_size,
                              hipStream_t stream) {
    const float* x    = (const float*)d_in[0];
    const float* Wqkv = (const float*)d_in[1];
    const float* bqkv = (const float*)d_in[2];
    const float* Wout = (const float*)d_in[3];
    const float* bout = (const float*)d_in[4];
    float* out = (float*)d_out;

    char* ws = (char*)d_ws;
    short* xs_res = (short*)(ws);               // 16,777,216 B  (xs, later reused as res)
    short* qtw    = (short*)(ws + 16777216);    // 16,777,216 B  (Q^T [bh][d][s])
    short* kw     = (short*)(ws + 33554432);    // 16,777,216 B  (K   [bh][s][d])
    short* vtw    = (short*)(ws + 50331648);    // 16,777,216 B  (V^T [bh][d][s])
    short* Wqkv_t = (short*)(ws + 67108864);    //    393,216 B
    short* Wout_t = (short*)(ws + 67502080);    //    131,072 B

    k_prep<<<dim3(3072), 256, 0, stream>>>(x, Wqkv, Wout, xs_res, Wqkv_t, Wout_t);
    k_qkv<<<dim3(1536), 256, 0, stream>>>(xs_res, Wqkv_t, bqkv, qtw, kw, vtw);
    k_attn<<<dim3(512), 256, 0, stream>>>(qtw, kw, vtw, xs_res);
    k_out<<<dim3(8, 2, 32), 256, 0, stream>>>(xs_res, Wout_t, bout, x, out);
}